// Round 1
// baseline (750.596 us; speedup 1.0000x reference)
//
#include <hip/hip_runtime.h>
#include <hip/hip_bf16.h>

#define B_N 8192
#define K_N 16
#define D_N 1024
#define C_N 512
#define BM  32

typedef __bf16 bf16x8 __attribute__((ext_vector_type(8)));
typedef float  f32x4  __attribute__((ext_vector_type(4)));
typedef float  f32x4v __attribute__((ext_vector_type(4)));
typedef unsigned int u32x4 __attribute__((ext_vector_type(4)));

static __device__ __forceinline__ unsigned short f2bf(float f) {
    union { float f; unsigned int u; } x; x.f = f;
    unsigned int r = x.u + 0x7FFFu + ((x.u >> 16) & 1u);   // RNE
    return (unsigned short)(r >> 16);
}

static __device__ __forceinline__ bf16x8 load_bf8(const unsigned short* p) {
    union { u32x4 u; bf16x8 v; } t;
    t.u = *(const u32x4*)p;
    return t.v;
}

static __device__ __forceinline__ bf16x8 zero_bf8() {
    union { u32x4 u; bf16x8 v; } t;
    u32x4 z = {0u, 0u, 0u, 0u};
    t.u = z;
    return t.v;
}

// ---------------- fused setup: histogram + scan + bucketed scatter ----------------
// Single block, 256 threads. Each thread owns 32 examples and a private LDS
// histogram row -> no atomics anywhere. Hillis-Steele scan over the 256 rows
// gives per-thread exclusive cursors; placement pass writes bucketed order.
__global__ __launch_bounds__(256) void prep(const int* __restrict__ slot_ids,
                                            const int* __restrict__ labels,
                                            int* __restrict__ counts,
                                            int* __restrict__ offsets_g,
                                            float* __restrict__ ce_sums,
                                            int* __restrict__ order_rows,
                                            int* __restrict__ lab_g) {
    __shared__ int h[256][K_N];
    __shared__ int g[256][K_N];
    __shared__ int soff[K_N];
    int t = threadIdx.x;
    int ids[32];

#pragma unroll
    for (int s = 0; s < K_N; ++s) h[t][s] = 0;
    // private row: no barrier needed before counting
#pragma unroll
    for (int i = 0; i < 32; ++i) {
        int b = i * 256 + t;
        int s = slot_ids[b];
        ids[i] = s;
        h[t][s]++;
    }
#pragma unroll
    for (int s = 0; s < K_N; ++s) g[t][s] = h[t][s];
    __syncthreads();

    // inclusive scan over thread-rows (Hillis-Steele, reg-staged)
    for (int d = 1; d < 256; d <<= 1) {
        int v[K_N];
        if (t >= d) {
#pragma unroll
            for (int s = 0; s < K_N; ++s) v[s] = h[t - d][s];
        }
        __syncthreads();
        if (t >= d) {
#pragma unroll
            for (int s = 0; s < K_N; ++s) h[t][s] += v[s];
        }
        __syncthreads();
    }

    if (t == 0) {
        int a = 0;
#pragma unroll
        for (int s = 0; s < K_N; ++s) {
            int c = h[255][s];
            counts[s] = c;
            soff[s] = a;
            offsets_g[s] = a;
            a += c;
        }
    }
    if (t < K_N) ce_sums[t] = 0.f;
    __syncthreads();

    // per-thread cursor = slot base + exclusive prefix of this thread's row
#pragma unroll
    for (int s = 0; s < K_N; ++s) h[t][s] = soff[s] + h[t][s] - g[t][s];

    // placement (rows private again: no barrier needed)
#pragma unroll
    for (int i = 0; i < 32; ++i) {
        int b = i * 256 + t;
        int s = ids[i];
        int idx = h[t][s]++;
        order_rows[idx] = b * K_N + s;   // flat row into concepts (b,s,:)
        lab_g[idx] = labels[b];
    }
}

// W fp32 (K,C,D) -> bf16
__global__ void convw(const float* __restrict__ W, unsigned short* __restrict__ Wb) {
    int i = (blockIdx.x * 256 + threadIdx.x) * 8;
    f32x4v a = *(const f32x4v*)(W + i);
    f32x4v b = *(const f32x4v*)(W + i + 4);
    u32x4 o;
    o[0] = (unsigned)f2bf(a[0]) | ((unsigned)f2bf(a[1]) << 16);
    o[1] = (unsigned)f2bf(a[2]) | ((unsigned)f2bf(a[3]) << 16);
    o[2] = (unsigned)f2bf(b[0]) | ((unsigned)f2bf(b[1]) << 16);
    o[3] = (unsigned)f2bf(b[2]) | ((unsigned)f2bf(b[3]) << 16);
    *(u32x4*)(Wb + i) = o;
}

// ---------------- GEMM + fused CE ----------------
// block: BM=32 rows x all 512 classes. 4 waves, each 128 classes (8 n-tiles of 16).
// A is read directly from concepts (fp32, gathered via order_rows) and converted
// to bf16 in-register -- no materialized gather pass.
__global__ __launch_bounds__(256) void gemm_ce(
        const float* __restrict__ concepts, const unsigned short* __restrict__ Wb,
        const float* __restrict__ bias, const int* __restrict__ counts,
        const int* __restrict__ offsets, const int* __restrict__ order_rows,
        const int* __restrict__ lab_g, float* __restrict__ ce_sums) {
    int s = blockIdx.y;
    int cnt = counts[s];
    int row0 = blockIdx.x * BM;
    if (row0 >= cnt) return;
    int nrows = min(BM, cnt - row0);
    int base = offsets[s];

    int tid = threadIdx.x;
    int wave = tid >> 6, lane = tid & 63;
    int col = lane & 15, quad = lane >> 4;
    int c0 = wave * 128;

    __shared__ int srow[BM];
    if (tid < BM)
        srow[tid] = order_rows[base + row0 + min(tid, nrows - 1)];
    __syncthreads();

    f32x4 acc[2][8];
    f32x4 zf = {0.f, 0.f, 0.f, 0.f};
#pragma unroll
    for (int m = 0; m < 2; ++m)
#pragma unroll
        for (int t = 0; t < 8; ++t) acc[m][t] = zf;

    const float* aptr[2];
    bool avalid[2];
#pragma unroll
    for (int m = 0; m < 2; ++m) {
        int lr = m * 16 + col;
        avalid[m] = lr < nrows;
        aptr[m] = concepts + (size_t)srow[lr] * D_N + quad * 8;
    }
    const unsigned short* bptr = Wb + ((size_t)s * C_N + c0 + col) * D_N + quad * 8;

    for (int k = 0; k < D_N; k += 32) {
        bf16x8 af[2];
#pragma unroll
        for (int m = 0; m < 2; ++m) {
            f32x4 a0 = *(const f32x4*)(aptr[m] + k);
            f32x4 a1 = *(const f32x4*)(aptr[m] + k + 4);
            bf16x8 v;
            v[0] = (__bf16)a0[0]; v[1] = (__bf16)a0[1];
            v[2] = (__bf16)a0[2]; v[3] = (__bf16)a0[3];
            v[4] = (__bf16)a1[0]; v[5] = (__bf16)a1[1];
            v[6] = (__bf16)a1[2]; v[7] = (__bf16)a1[3];
            af[m] = avalid[m] ? v : zero_bf8();
        }
        bf16x8 bfr[8];
#pragma unroll
        for (int t = 0; t < 8; ++t)
            bfr[t] = load_bf8(bptr + (size_t)t * 16 * D_N + k);
#pragma unroll
        for (int m = 0; m < 2; ++m)
#pragma unroll
            for (int t = 0; t < 8; ++t)
                acc[m][t] = __builtin_amdgcn_mfma_f32_16x16x32_bf16(af[m], bfr[t], acc[m][t], 0, 0, 0);
    }

    // epilogue: bias + per-row logsumexp + label logit + CE
    __shared__ float smax[4][BM];
    __shared__ float ssum[4][BM];
    __shared__ float gmax[BM];
    __shared__ float slab[BM];

#pragma unroll
    for (int t = 0; t < 8; ++t) {
        float bv = bias[(size_t)s * C_N + c0 + t * 16 + col];
#pragma unroll
        for (int m = 0; m < 2; ++m)
#pragma unroll
            for (int r = 0; r < 4; ++r) acc[m][t][r] += bv;
    }

    // per-wave row max over its 128 classes
#pragma unroll
    for (int m = 0; m < 2; ++m)
#pragma unroll
        for (int r = 0; r < 4; ++r) {
            float v = acc[m][0][r];
#pragma unroll
            for (int t = 1; t < 8; ++t) v = fmaxf(v, acc[m][t][r]);
            v = fmaxf(v, __shfl_xor(v, 1, 64));
            v = fmaxf(v, __shfl_xor(v, 2, 64));
            v = fmaxf(v, __shfl_xor(v, 4, 64));
            v = fmaxf(v, __shfl_xor(v, 8, 64));
            if (col == 0) smax[wave][m * 16 + quad * 4 + r] = v;
        }
    __syncthreads();
    if (tid < BM)
        gmax[tid] = fmaxf(fmaxf(smax[0][tid], smax[1][tid]),
                          fmaxf(smax[2][tid], smax[3][tid]));
    __syncthreads();

    // per-wave sum(exp) + label-logit capture
#pragma unroll
    for (int m = 0; m < 2; ++m)
#pragma unroll
        for (int r = 0; r < 4; ++r) {
            int row = m * 16 + quad * 4 + r;
            float gm = gmax[row];
            int lab = (row < nrows) ? lab_g[base + row0 + row] : -1;
            float sv = 0.f;
#pragma unroll
            for (int t = 0; t < 8; ++t) {
                float x = acc[m][t][r];
                sv += __expf(x - gm);
                if (c0 + t * 16 + col == lab) slab[row] = x;
            }
            sv += __shfl_xor(sv, 1, 64);
            sv += __shfl_xor(sv, 2, 64);
            sv += __shfl_xor(sv, 4, 64);
            sv += __shfl_xor(sv, 8, 64);
            if (col == 0) ssum[wave][row] = sv;
        }
    __syncthreads();

    if (wave == 0) {
        float ce = 0.f;
        if (lane < nrows) {
            float gs = ssum[0][lane] + ssum[1][lane] + ssum[2][lane] + ssum[3][lane];
            ce = gmax[lane] + __logf(gs) - slab[lane];
        }
        ce += __shfl_xor(ce, 1, 64);
        ce += __shfl_xor(ce, 2, 64);
        ce += __shfl_xor(ce, 4, 64);
        ce += __shfl_xor(ce, 8, 64);
        ce += __shfl_xor(ce, 16, 64);
        ce += __shfl_xor(ce, 32, 64);
        if (lane == 0) atomicAdd(&ce_sums[s], ce);
    }
}

__global__ void finalize(const int* __restrict__ counts, const float* __restrict__ ce_sums,
                         float* __restrict__ out) {
    if (threadIdx.x == 0 && blockIdx.x == 0) {
        float tot = 0.f; int np = 0;
        for (int s = 0; s < K_N; ++s) {
            int c = counts[s];
            if (c > 0) { tot += ce_sums[s] / (float)c; np++; }
        }
        out[0] = tot / (float)(np > 0 ? np : 1);
    }
}

extern "C" void kernel_launch(void* const* d_in, const int* in_sizes, int n_in,
                              void* d_out, int out_size, void* d_ws, size_t ws_size,
                              hipStream_t stream) {
    const float* concepts = (const float*)d_in[0];
    const int*   slot_ids = (const int*)d_in[1];
    const int*   labels   = (const int*)d_in[2];
    const float* W        = (const float*)d_in[3];
    const float* bias     = (const float*)d_in[4];
    float* out = (float*)d_out;

    char* ws = (char*)d_ws;
    int*   counts     = (int*)(ws + 0);
    int*   offsets    = (int*)(ws + 64);
    float* ce_sums    = (float*)(ws + 192);
    int*   order_rows = (int*)(ws + 256);
    int*   lab_g      = (int*)(ws + 256 + 4 * B_N);
    unsigned short* Wb = (unsigned short*)(ws + 131072);
    // total ws use: 131072 + 16 MiB ~= 16.9 MB

    convw<<<(K_N * C_N * D_N) / (256 * 8), 256, 0, stream>>>(W, Wb);
    prep<<<1, 256, 0, stream>>>(slot_ids, labels, counts, offsets, ce_sums, order_rows, lab_g);
    gemm_ce<<<dim3(B_N / BM, K_N), 256, 0, stream>>>(concepts, Wb, bias, counts, offsets,
                                                     order_rows, lab_g, ce_sums);
    finalize<<<1, 1, 0, stream>>>(counts, ce_sums, out);
}

// Round 2
// 733.640 us; speedup vs baseline: 1.0231x; 1.0231x over previous
//
#include <hip/hip_runtime.h>
#include <hip/hip_bf16.h>

#define B_N 8192
#define K_N 16
#define D_N 1024
#define C_N 512
#define BM  16
#define CONVW_BLOCKS ((K_N * C_N * D_N) / (256 * 8))   /* 4096 */
#define GEMM_BLOCKS  (B_N / BM + K_N)                  /* 528: upper bound on sum ceil(cnt/BM) */

typedef __bf16 bf16x8 __attribute__((ext_vector_type(8)));
typedef float  f32x4  __attribute__((ext_vector_type(4)));
typedef unsigned int u32x4 __attribute__((ext_vector_type(4)));

static __device__ __forceinline__ unsigned short f2bf(float f) {
    union { float f; unsigned int u; } x; x.f = f;
    unsigned int r = x.u + 0x7FFFu + ((x.u >> 16) & 1u);   // RNE
    return (unsigned short)(r >> 16);
}

static __device__ __forceinline__ bf16x8 load_bf8(const unsigned short* p) {
    union { u32x4 u; bf16x8 v; } t;
    t.u = *(const u32x4*)p;
    return t.v;
}

static __device__ __forceinline__ bf16x8 zero_bf8() {
    union { u32x4 u; bf16x8 v; } t;
    u32x4 z = {0u, 0u, 0u, 0u};
    t.u = z;
    return t.v;
}

// ---------------- fused setup ----------------
// Blocks [0, CONVW_BLOCKS): W fp32 -> bf16 conversion.
// Block CONVW_BLOCKS: histogram + scan + bucketed scatter + block-base prefix
// (runs concurrently, hidden under convw; gemm depends on both).
__global__ __launch_bounds__(256) void setup(
        const float* __restrict__ W, unsigned short* __restrict__ Wb,
        const int* __restrict__ slot_ids, const int* __restrict__ labels,
        int* __restrict__ counts, int* __restrict__ offsets_g,
        int* __restrict__ blk_base, int* __restrict__ done,
        float* __restrict__ ce_sums, int* __restrict__ order_rows,
        int* __restrict__ lab_g) {
    __shared__ int h[256][K_N];
    __shared__ int soff[K_N];
    int t = threadIdx.x;

    if (blockIdx.x < CONVW_BLOCKS) {
        size_t i = ((size_t)blockIdx.x * 256 + t) * 8;
        f32x4 a = *(const f32x4*)(W + i);
        f32x4 b = *(const f32x4*)(W + i + 4);
        u32x4 o;
        o[0] = (unsigned)f2bf(a[0]) | ((unsigned)f2bf(a[1]) << 16);
        o[1] = (unsigned)f2bf(a[2]) | ((unsigned)f2bf(a[3]) << 16);
        o[2] = (unsigned)f2bf(b[0]) | ((unsigned)f2bf(b[1]) << 16);
        o[3] = (unsigned)f2bf(b[2]) | ((unsigned)f2bf(b[3]) << 16);
        *(u32x4*)(Wb + i) = o;
        return;
    }

    // ---- prep (single block) ----
    int ids[32];
    int own[K_N];

#pragma unroll
    for (int s = 0; s < K_N; ++s) h[t][s] = 0;
    // private histogram row: no atomics, no barrier needed while counting
#pragma unroll
    for (int i = 0; i < 32; ++i) {
        int b = i * 256 + t;
        int s = slot_ids[b];
        ids[i] = s;
        h[t][s]++;
    }
#pragma unroll
    for (int s = 0; s < K_N; ++s) own[s] = h[t][s];
    __syncthreads();

    // inclusive scan over the 256 thread-rows (Hillis-Steele)
    for (int d = 1; d < 256; d <<= 1) {
        int v[K_N];
        if (t >= d) {
#pragma unroll
            for (int s = 0; s < K_N; ++s) v[s] = h[t - d][s];
        }
        __syncthreads();
        if (t >= d) {
#pragma unroll
            for (int s = 0; s < K_N; ++s) h[t][s] += v[s];
        }
        __syncthreads();
    }

    if (t == 0) {
        int a = 0, nb = 0;
        blk_base[0] = 0;
#pragma unroll
        for (int s = 0; s < K_N; ++s) {
            int c = h[255][s];
            counts[s] = c;
            soff[s] = a;
            offsets_g[s] = a;
            a += c;
            nb += (c + BM - 1) / BM;
            blk_base[s + 1] = nb;
        }
        *done = 0;
    }
    if (t < K_N) ce_sums[t] = 0.f;
    __syncthreads();

    // per-thread cursor = slot base + exclusive prefix of this thread's row
#pragma unroll
    for (int s = 0; s < K_N; ++s) own[s] = soff[s] + h[t][s] - own[s];

#pragma unroll
    for (int i = 0; i < 32; ++i) {
        int b = i * 256 + t;
        int s = ids[i];
        int idx = own[s]++;
        order_rows[idx] = b * K_N + s;   // flat row into concepts (b,s,:)
        lab_g[idx] = labels[b];
    }
}

// ---------------- GEMM + fused CE + fused finalize ----------------
// BM=16 rows x all 512 classes per block; 4 waves x 128 classes (8 n-tiles).
// Exact 1D grid via blk_base prefix (even CU load balance, ~2 blocks/CU).
// Last block to finish computes the final scalar (atomic done-counter).
__global__ __launch_bounds__(256) void gemm_ce(
        const float* __restrict__ concepts, const unsigned short* __restrict__ Wb,
        const float* __restrict__ bias, const int* __restrict__ counts,
        const int* __restrict__ offsets, const int* __restrict__ blk_base,
        const int* __restrict__ order_rows, const int* __restrict__ lab_g,
        int* __restrict__ done, float* __restrict__ ce_sums,
        float* __restrict__ out) {
    __shared__ int srow[BM];
    __shared__ float smax[4][BM];
    __shared__ float ssum[4][BM];
    __shared__ float gmax[BM];
    __shared__ float slab[BM];

    int bid = blockIdx.x;
    int nb_total = blk_base[K_N];
    int tid = threadIdx.x;

    if (bid < nb_total) {
        // locate slot for this block
        int s = 0;
        while (s < K_N - 1 && bid >= blk_base[s + 1]) ++s;
        int cnt = counts[s];
        int base = offsets[s];
        int row0 = (bid - blk_base[s]) * BM;
        int nrows = min(BM, cnt - row0);

        int wave = tid >> 6, lane = tid & 63;
        int col = lane & 15, quad = lane >> 4;
        int c0 = wave * 128;

        if (tid < BM)
            srow[tid] = order_rows[base + row0 + min(tid, nrows - 1)];
        __syncthreads();

        f32x4 acc[8];
        f32x4 zf = {0.f, 0.f, 0.f, 0.f};
#pragma unroll
        for (int t8 = 0; t8 < 8; ++t8) acc[t8] = zf;

        bool avalid = col < nrows;
        const float* aptr = concepts + (size_t)srow[col] * D_N + quad * 8;
        const unsigned short* bptr = Wb + ((size_t)s * C_N + c0 + col) * D_N + quad * 8;

        for (int k = 0; k < D_N; k += 32) {
            f32x4 a0 = *(const f32x4*)(aptr + k);
            f32x4 a1 = *(const f32x4*)(aptr + k + 4);
            bf16x8 v;
            v[0] = (__bf16)a0[0]; v[1] = (__bf16)a0[1];
            v[2] = (__bf16)a0[2]; v[3] = (__bf16)a0[3];
            v[4] = (__bf16)a1[0]; v[5] = (__bf16)a1[1];
            v[6] = (__bf16)a1[2]; v[7] = (__bf16)a1[3];
            bf16x8 af = avalid ? v : zero_bf8();
            bf16x8 bfr[8];
#pragma unroll
            for (int t8 = 0; t8 < 8; ++t8)
                bfr[t8] = load_bf8(bptr + (size_t)t8 * 16 * D_N + k);
#pragma unroll
            for (int t8 = 0; t8 < 8; ++t8)
                acc[t8] = __builtin_amdgcn_mfma_f32_16x16x32_bf16(af, bfr[t8], acc[t8], 0, 0, 0);
        }

        // ---- epilogue: bias + per-row logsumexp + label logit + CE ----
#pragma unroll
        for (int t8 = 0; t8 < 8; ++t8) {
            float bv = bias[(size_t)s * C_N + c0 + t8 * 16 + col];
#pragma unroll
            for (int r = 0; r < 4; ++r) acc[t8][r] += bv;
        }

        // per-wave row max over its 128 classes
#pragma unroll
        for (int r = 0; r < 4; ++r) {
            int row = quad * 4 + r;
            float v = acc[0][r];
#pragma unroll
            for (int t8 = 1; t8 < 8; ++t8) v = fmaxf(v, acc[t8][r]);
            v = fmaxf(v, __shfl_xor(v, 1, 64));
            v = fmaxf(v, __shfl_xor(v, 2, 64));
            v = fmaxf(v, __shfl_xor(v, 4, 64));
            v = fmaxf(v, __shfl_xor(v, 8, 64));
            if (col == 0) smax[wave][row] = v;
        }
        __syncthreads();
        if (tid < BM)
            gmax[tid] = fmaxf(fmaxf(smax[0][tid], smax[1][tid]),
                              fmaxf(smax[2][tid], smax[3][tid]));
        __syncthreads();

        // per-wave sum(exp) + label-logit capture
#pragma unroll
        for (int r = 0; r < 4; ++r) {
            int row = quad * 4 + r;
            float gm = gmax[row];
            int lab = (row < nrows) ? lab_g[base + row0 + row] : -1;
            float sv = 0.f;
#pragma unroll
            for (int t8 = 0; t8 < 8; ++t8) {
                float x = acc[t8][r];
                sv += __expf(x - gm);
                if (c0 + t8 * 16 + col == lab) slab[row] = x;
            }
            sv += __shfl_xor(sv, 1, 64);
            sv += __shfl_xor(sv, 2, 64);
            sv += __shfl_xor(sv, 4, 64);
            sv += __shfl_xor(sv, 8, 64);
            if (col == 0) ssum[wave][row] = sv;
        }
        __syncthreads();

        if (wave == 0) {
            float ce = 0.f;
            if (lane < nrows) {
                float gs = ssum[0][lane] + ssum[1][lane] + ssum[2][lane] + ssum[3][lane];
                ce = gmax[lane] + __logf(gs) - slab[lane];
            }
            ce += __shfl_xor(ce, 1, 64);
            ce += __shfl_xor(ce, 2, 64);
            ce += __shfl_xor(ce, 4, 64);
            ce += __shfl_xor(ce, 8, 64);
            ce += __shfl_xor(ce, 16, 64);
            ce += __shfl_xor(ce, 32, 64);
            if (lane == 0) atomicAdd(&ce_sums[s], ce);
        }
    }

    // ---- completion: last block computes the final scalar ----
    __syncthreads();
    if (tid == 0) {
        __threadfence();
        int old = atomicAdd(done, 1);
        if (old == (int)gridDim.x - 1) {
            float tot = 0.f; int np = 0;
            for (int s2 = 0; s2 < K_N; ++s2) {
                int c = counts[s2];
                if (c > 0) {
                    float cs = atomicAdd(&ce_sums[s2], 0.0f);   // device-scope atomic read
                    tot += cs / (float)c; np++;
                }
            }
            out[0] = tot / (float)(np > 0 ? np : 1);
        }
    }
}

extern "C" void kernel_launch(void* const* d_in, const int* in_sizes, int n_in,
                              void* d_out, int out_size, void* d_ws, size_t ws_size,
                              hipStream_t stream) {
    const float* concepts = (const float*)d_in[0];
    const int*   slot_ids = (const int*)d_in[1];
    const int*   labels   = (const int*)d_in[2];
    const float* W        = (const float*)d_in[3];
    const float* bias     = (const float*)d_in[4];
    float* out = (float*)d_out;

    char* ws = (char*)d_ws;
    int*   counts     = (int*)(ws + 0);
    int*   offsets    = (int*)(ws + 64);
    int*   blk_base   = (int*)(ws + 128);   // 17 ints
    int*   done       = (int*)(ws + 256);
    float* ce_sums    = (float*)(ws + 320);
    int*   order_rows = (int*)(ws + 512);
    int*   lab_g      = (int*)(ws + 512 + 4 * B_N);
    unsigned short* Wb = (unsigned short*)(ws + 131072);
    // total ws use: 131072 + 16 MiB ~= 16.9 MB

    setup<<<CONVW_BLOCKS + 1, 256, 0, stream>>>(W, Wb, slot_ids, labels, counts, offsets,
                                                blk_base, done, ce_sums, order_rows, lab_g);
    gemm_ce<<<GEMM_BLOCKS, 256, 0, stream>>>(concepts, Wb, bias, counts, offsets, blk_base,
                                             order_rows, lab_g, done, ce_sums, out);
}

// Round 3
// 720.355 us; speedup vs baseline: 1.0420x; 1.0184x over previous
//
#include <hip/hip_runtime.h>
#include <hip/hip_bf16.h>

#define B_N 8192
#define K_N 16
#define D_N 1024
#define C_N 512
#define BM  64
#define CONVW_BLOCKS ((K_N * C_N * D_N) / (256 * 8))   /* 4096 */
#define GEMM_BLOCKS  (B_N / BM + K_N)                  /* 144; 144 % 8 == 0 (bijective swizzle) */

typedef __bf16 bf16x8 __attribute__((ext_vector_type(8)));
typedef float  f32x4  __attribute__((ext_vector_type(4)));
typedef unsigned int u32x4 __attribute__((ext_vector_type(4)));

static __device__ __forceinline__ unsigned short f2bf(float f) {
    union { float f; unsigned int u; } x; x.f = f;
    unsigned int r = x.u + 0x7FFFu + ((x.u >> 16) & 1u);   // RNE
    return (unsigned short)(r >> 16);
}

static __device__ __forceinline__ bf16x8 load_bf8(const unsigned short* p) {
    union { u32x4 u; bf16x8 v; } t;
    t.u = *(const u32x4*)p;
    return t.v;
}

static __device__ __forceinline__ bf16x8 zero_bf8() {
    union { u32x4 u; bf16x8 v; } t;
    u32x4 z = {0u, 0u, 0u, 0u};
    t.u = z;
    return t.v;
}

// ---------------- fused setup ----------------
// Block 0: histogram + scan + bucketed scatter + block-base prefix (serial part
// starts FIRST so it hides under the 4096 convw blocks).
// Blocks [1, CONVW_BLOCKS]: W fp32 -> bf16 conversion.
__global__ __launch_bounds__(256) void setup(
        const float* __restrict__ W, unsigned short* __restrict__ Wb,
        const int* __restrict__ slot_ids, const int* __restrict__ labels,
        int* __restrict__ counts, int* __restrict__ offsets_g,
        int* __restrict__ blk_base, int* __restrict__ done,
        float* __restrict__ ce_sums, int* __restrict__ order_rows,
        int* __restrict__ lab_g) {
    __shared__ int h[256][K_N];
    __shared__ int soff[K_N];
    int t = threadIdx.x;

    if (blockIdx.x > 0) {
        size_t i = ((size_t)(blockIdx.x - 1) * 256 + t) * 8;
        f32x4 a = *(const f32x4*)(W + i);
        f32x4 b = *(const f32x4*)(W + i + 4);
        u32x4 o;
        o[0] = (unsigned)f2bf(a[0]) | ((unsigned)f2bf(a[1]) << 16);
        o[1] = (unsigned)f2bf(a[2]) | ((unsigned)f2bf(a[3]) << 16);
        o[2] = (unsigned)f2bf(b[0]) | ((unsigned)f2bf(b[1]) << 16);
        o[3] = (unsigned)f2bf(b[2]) | ((unsigned)f2bf(b[3]) << 16);
        *(u32x4*)(Wb + i) = o;
        return;
    }

    // ---- prep (block 0) ----
    int ids[32];
    int own[K_N];

#pragma unroll
    for (int s = 0; s < K_N; ++s) h[t][s] = 0;
    // private histogram row: no atomics, no barrier needed while counting
#pragma unroll
    for (int i = 0; i < 32; ++i) {
        int b = i * 256 + t;
        int s = slot_ids[b];
        ids[i] = s;
        h[t][s]++;
    }
#pragma unroll
    for (int s = 0; s < K_N; ++s) own[s] = h[t][s];
    __syncthreads();

    // inclusive scan over the 256 thread-rows (Hillis-Steele)
    for (int d = 1; d < 256; d <<= 1) {
        int v[K_N];
        if (t >= d) {
#pragma unroll
            for (int s = 0; s < K_N; ++s) v[s] = h[t - d][s];
        }
        __syncthreads();
        if (t >= d) {
#pragma unroll
            for (int s = 0; s < K_N; ++s) h[t][s] += v[s];
        }
        __syncthreads();
    }

    if (t == 0) {
        int a = 0, nb = 0;
        blk_base[0] = 0;
#pragma unroll
        for (int s = 0; s < K_N; ++s) {
            int c = h[255][s];
            counts[s] = c;
            soff[s] = a;
            offsets_g[s] = a;
            a += c;
            nb += (c + BM - 1) / BM;
            blk_base[s + 1] = nb;
        }
        *done = 0;
    }
    if (t < K_N) ce_sums[t] = 0.f;
    __syncthreads();

    // per-thread cursor = slot base + exclusive prefix of this thread's row
#pragma unroll
    for (int s = 0; s < K_N; ++s) own[s] = soff[s] + h[t][s] - own[s];

#pragma unroll
    for (int i = 0; i < 32; ++i) {
        int b = i * 256 + t;
        int s = ids[i];
        int idx = own[s]++;
        order_rows[idx] = b * K_N + s;   // flat row into concepts (b,s,:)
        lab_g[idx] = labels[b];
    }
}

// ---------------- GEMM + fused CE + fused finalize ----------------
// BM=64 rows x all 512 classes per block; 4 waves x 128 classes; acc[4][8].
// 144 blocks <= 256 CUs -> at most 1 block/CU (no tail CU runs 2 blocks);
// B-panel traffic = 144 MiB total (vs 528 MiB at BM=16).
// XCD swizzle: consecutive work-ids (same slot, same 1 MiB Wb panel) map to
// the same XCD so the panel stays L2-resident. 144 % 8 == 0 -> bijective.
// Last block to finish computes the final scalar (atomic done-counter).
__global__ __launch_bounds__(256, 1) void gemm_ce(
        const float* __restrict__ concepts, const unsigned short* __restrict__ Wb,
        const float* __restrict__ bias, const int* __restrict__ counts,
        const int* __restrict__ offsets, const int* __restrict__ blk_base,
        const int* __restrict__ order_rows, const int* __restrict__ lab_g,
        int* __restrict__ done, float* __restrict__ ce_sums,
        float* __restrict__ out) {
    __shared__ int srow[BM];
    __shared__ float smax[4][BM];
    __shared__ float ssum[4][BM];
    __shared__ float gmax[BM];
    __shared__ float slab[BM];

    // XCD-aware swizzle (8 XCDs, GEMM_BLOCKS % 8 == 0)
    int bid = (blockIdx.x % 8) * (GEMM_BLOCKS / 8) + blockIdx.x / 8;
    int nb_total = blk_base[K_N];
    int tid = threadIdx.x;

    if (bid < nb_total) {
        // locate slot for this block
        int s = 0;
        while (s < K_N - 1 && bid >= blk_base[s + 1]) ++s;
        int cnt = counts[s];
        int base = offsets[s];
        int row0 = (bid - blk_base[s]) * BM;
        int nrows = min(BM, cnt - row0);

        int wave = tid >> 6, lane = tid & 63;
        int col = lane & 15, quad = lane >> 4;
        int c0 = wave * 128;

        if (tid < BM)
            srow[tid] = order_rows[base + row0 + min(tid, nrows - 1)];
        __syncthreads();

        f32x4 acc[4][8];
        f32x4 zf = {0.f, 0.f, 0.f, 0.f};
#pragma unroll
        for (int m = 0; m < 4; ++m)
#pragma unroll
            for (int t8 = 0; t8 < 8; ++t8) acc[m][t8] = zf;

        const float* aptr[4];
        bool avalid[4];
#pragma unroll
        for (int m = 0; m < 4; ++m) {
            int lr = m * 16 + col;
            avalid[m] = lr < nrows;
            aptr[m] = concepts + (size_t)srow[lr] * D_N + quad * 8;
        }
        const unsigned short* bptr = Wb + ((size_t)s * C_N + c0 + col) * D_N + quad * 8;

        for (int k = 0; k < D_N; k += 32) {
            bf16x8 af[4];
#pragma unroll
            for (int m = 0; m < 4; ++m) {
                f32x4 a0 = *(const f32x4*)(aptr[m] + k);
                f32x4 a1 = *(const f32x4*)(aptr[m] + k + 4);
                bf16x8 v;
                v[0] = (__bf16)a0[0]; v[1] = (__bf16)a0[1];
                v[2] = (__bf16)a0[2]; v[3] = (__bf16)a0[3];
                v[4] = (__bf16)a1[0]; v[5] = (__bf16)a1[1];
                v[6] = (__bf16)a1[2]; v[7] = (__bf16)a1[3];
                af[m] = avalid[m] ? v : zero_bf8();
            }
            bf16x8 bfr[8];
#pragma unroll
            for (int t8 = 0; t8 < 8; ++t8)
                bfr[t8] = load_bf8(bptr + (size_t)t8 * 16 * D_N + k);
#pragma unroll
            for (int m = 0; m < 4; ++m)
#pragma unroll
                for (int t8 = 0; t8 < 8; ++t8)
                    acc[m][t8] = __builtin_amdgcn_mfma_f32_16x16x32_bf16(af[m], bfr[t8], acc[m][t8], 0, 0, 0);
        }

        // ---- epilogue: bias + per-row logsumexp + label logit + CE ----
#pragma unroll
        for (int t8 = 0; t8 < 8; ++t8) {
            float bv = bias[(size_t)s * C_N + c0 + t8 * 16 + col];
#pragma unroll
            for (int m = 0; m < 4; ++m)
#pragma unroll
                for (int r = 0; r < 4; ++r) acc[m][t8][r] += bv;
        }

        // per-wave row max over its 128 classes
#pragma unroll
        for (int m = 0; m < 4; ++m)
#pragma unroll
            for (int r = 0; r < 4; ++r) {
                int row = m * 16 + quad * 4 + r;
                float v = acc[m][0][r];
#pragma unroll
                for (int t8 = 1; t8 < 8; ++t8) v = fmaxf(v, acc[m][t8][r]);
                v = fmaxf(v, __shfl_xor(v, 1, 64));
                v = fmaxf(v, __shfl_xor(v, 2, 64));
                v = fmaxf(v, __shfl_xor(v, 4, 64));
                v = fmaxf(v, __shfl_xor(v, 8, 64));
                if (col == 0) smax[wave][row] = v;
            }
        __syncthreads();
        if (tid < BM)
            gmax[tid] = fmaxf(fmaxf(smax[0][tid], smax[1][tid]),
                              fmaxf(smax[2][tid], smax[3][tid]));
        __syncthreads();

        // per-wave sum(exp) + label-logit capture
#pragma unroll
        for (int m = 0; m < 4; ++m)
#pragma unroll
            for (int r = 0; r < 4; ++r) {
                int row = m * 16 + quad * 4 + r;
                float gm = gmax[row];
                int lab = (row < nrows) ? lab_g[base + row0 + row] : -1;
                float sv = 0.f;
#pragma unroll
                for (int t8 = 0; t8 < 8; ++t8) {
                    float x = acc[m][t8][r];
                    sv += __expf(x - gm);
                    if (c0 + t8 * 16 + col == lab) slab[row] = x;
                }
                sv += __shfl_xor(sv, 1, 64);
                sv += __shfl_xor(sv, 2, 64);
                sv += __shfl_xor(sv, 4, 64);
                sv += __shfl_xor(sv, 8, 64);
                if (col == 0) ssum[wave][row] = sv;
            }
        __syncthreads();

        if (wave == 0) {
            float ce = 0.f;
            if (lane < nrows) {
                float gs = ssum[0][lane] + ssum[1][lane] + ssum[2][lane] + ssum[3][lane];
                ce = gmax[lane] + __logf(gs) - slab[lane];
            }
            ce += __shfl_xor(ce, 1, 64);
            ce += __shfl_xor(ce, 2, 64);
            ce += __shfl_xor(ce, 4, 64);
            ce += __shfl_xor(ce, 8, 64);
            ce += __shfl_xor(ce, 16, 64);
            ce += __shfl_xor(ce, 32, 64);
            if (lane == 0) atomicAdd(&ce_sums[s], ce);
        }
    }

    // ---- completion: last block computes the final scalar ----
    __syncthreads();
    if (tid == 0) {
        __threadfence();
        int old = atomicAdd(done, 1);
        if (old == (int)gridDim.x - 1) {
            float tot = 0.f; int np = 0;
            for (int s2 = 0; s2 < K_N; ++s2) {
                int c = counts[s2];
                if (c > 0) {
                    float cs = atomicAdd(&ce_sums[s2], 0.0f);   // device-scope atomic read
                    tot += cs / (float)c; np++;
                }
            }
            out[0] = tot / (float)(np > 0 ? np : 1);
        }
    }
}

extern "C" void kernel_launch(void* const* d_in, const int* in_sizes, int n_in,
                              void* d_out, int out_size, void* d_ws, size_t ws_size,
                              hipStream_t stream) {
    const float* concepts = (const float*)d_in[0];
    const int*   slot_ids = (const int*)d_in[1];
    const int*   labels   = (const int*)d_in[2];
    const float* W        = (const float*)d_in[3];
    const float* bias     = (const float*)d_in[4];
    float* out = (float*)d_out;

    char* ws = (char*)d_ws;
    int*   counts     = (int*)(ws + 0);
    int*   offsets    = (int*)(ws + 64);
    int*   blk_base   = (int*)(ws + 128);   // 17 ints
    int*   done       = (int*)(ws + 256);
    float* ce_sums    = (float*)(ws + 320);
    int*   order_rows = (int*)(ws + 512);
    int*   lab_g      = (int*)(ws + 512 + 4 * B_N);
    unsigned short* Wb = (unsigned short*)(ws + 131072);
    // total ws use: 131072 + 16 MiB ~= 16.9 MB

    setup<<<CONVW_BLOCKS + 1, 256, 0, stream>>>(W, Wb, slot_ids, labels, counts, offsets,
                                                blk_base, done, ce_sums, order_rows, lab_g);
    gemm_ce<<<GEMM_BLOCKS, 256, 0, stream>>>(concepts, Wb, bias, counts, offsets, blk_base,
                                             order_rows, lab_g, done, ce_sums, out);
}